// Round 1
// 175.885 us; speedup vs baseline: 1.0102x; 1.0102x over previous
//
#include <hip/hip_runtime.h>
#include <math.h>

// ManifoldAlignmentLoss: B=256, D=512, N=50000, A=8, K=5
// Sparse pair-list strategy (R2 structure):
//   prep -> match (pair compaction) -> dot -> topk
// R3 lesson: fusing match+dot starves the grid (196 blocks < 256 CUs -> 7% occ).
// R5 change: dot was latency-bound (~45us vs ~10us BW floor) with one wave/pair
// (only 4 loads in flight/lane, niter~4 so the 2-deep pipeline never filled).
// Now: 16-lane groups, one pair per group, 16 independent float4 loads per lane
// (4x MLP), single sweep over the pair list, 4-step shfl reduce.

constexpr int D = 512;
constexpr int A = 8;
constexpr int K_NEI = 5;
constexpr int SLOTS = 512;        // per-b sim bucket capacity (mean ~130)
constexpr int CSTRIDE = 16;       // counter padding: 64B per counter line
constexpr int PAIR_CAP = 65536;   // global pair list capacity (mean ~33K)
constexpr int LDS_PAIR_CAP = 1024;
constexpr int DOT_BLOCKS = 2304;  // x16 groups = 36864 groups >= np (33K mean, ~20 sigma)

__device__ __forceinline__ float wave_reduce_add(float v) {
    #pragma unroll
    for (int m = 1; m < 64; m <<= 1) v += __shfl_xor(v, m, 64);
    return v;
}

// ---------------- prep: normalize z rows, pack target attrs, zero state ----
// grid = B blocks x 64 threads
__global__ __launch_bounds__(64) void prep_kernel(
    const float* __restrict__ z, const int* __restrict__ tattr,
    float* __restrict__ z_norm, unsigned* __restrict__ tpacked,
    int* __restrict__ counters, int* __restrict__ npairs,
    float* __restrict__ out)
{
    const int b = blockIdx.x;
    const int lane = threadIdx.x;
    const float4* zrow = (const float4*)(z + (size_t)b * D);
    float4 v0 = zrow[lane * 2 + 0];
    float4 v1 = zrow[lane * 2 + 1];
    float ss = v0.x*v0.x + v0.y*v0.y + v0.z*v0.z + v0.w*v0.w
             + v1.x*v1.x + v1.y*v1.y + v1.z*v1.z + v1.w*v1.w;
    ss = wave_reduce_add(ss);
    const float scale = 1.0f / fmaxf(sqrtf(ss), 1e-12f);
    v0.x *= scale; v0.y *= scale; v0.z *= scale; v0.w *= scale;
    v1.x *= scale; v1.y *= scale; v1.z *= scale; v1.w *= scale;
    float4* orow = (float4*)(z_norm + (size_t)b * D);
    orow[lane * 2 + 0] = v0;
    orow[lane * 2 + 1] = v1;
    if (lane == 0) {
        unsigned p = 0;
        #pragma unroll
        for (int a = 0; a < A; a++)
            p |= ((unsigned)tattr[b * A + a] & 0xFu) << (4 * a);
        tpacked[b] = p;
        counters[b * CSTRIDE] = 0;
        if (b == 0) { *npairs = 0; out[0] = 0.0f; }
    }
}

// ---------------- match: one thread per train row, compact pairs ----------
// grid = ceil(N/256) blocks x 256 threads
__global__ __launch_bounds__(256) void match_kernel(
    const int* __restrict__ trattr, const unsigned* __restrict__ tpacked,
    unsigned* __restrict__ pairs, int* __restrict__ npairs, int N)
{
    __shared__ unsigned s_tp[256];
    __shared__ unsigned s_pairs[LDS_PAIR_CAP];
    __shared__ int s_cnt, s_base;

    const int tid = threadIdx.x;
    const int n = blockIdx.x * 256 + tid;
    s_tp[tid] = tpacked[tid];
    if (tid == 0) s_cnt = 0;
    __syncthreads();

    if (n < N) {
        const int4* a4 = (const int4*)(trattr + (size_t)n * A);
        const int4 x = a4[0], y = a4[1];
        const unsigned p =
             ((unsigned)x.x & 0xFu)        | (((unsigned)x.y & 0xFu) << 4)
           | (((unsigned)x.z & 0xFu) << 8)  | (((unsigned)x.w & 0xFu) << 12)
           | (((unsigned)y.x & 0xFu) << 16) | (((unsigned)y.y & 0xFu) << 20)
           | (((unsigned)y.z & 0xFu) << 24) | (((unsigned)y.w & 0xFu) << 28);

        const uint4* tp4 = (const uint4*)s_tp;
        #pragma unroll 4
        for (int bq = 0; bq < 64; bq++) {
            const uint4 t = tp4[bq];
            #pragma unroll
            for (int j = 0; j < 4; j++) {
                const unsigned tv = (j == 0) ? t.x : (j == 1) ? t.y : (j == 2) ? t.z : t.w;
                const unsigned yv = p ^ tv;
                // hi bit of each nibble set iff nibble nonzero
                const unsigned nzhi = ((((yv & 0x77777777u) + 0x77777777u) | yv) & 0x88888888u);
                if (__popc(nzhi) <= 1) {   // >= A-1 matching attrs
                    const int idx = atomicAdd(&s_cnt, 1);
                    if (idx < LDS_PAIR_CAP)
                        s_pairs[idx] = ((unsigned)n << 8) | (unsigned)(bq * 4 + j);
                }
            }
        }
    }
    __syncthreads();
    const int cnt = min(s_cnt, LDS_PAIR_CAP);
    if (tid == 0) s_base = atomicAdd(npairs, cnt);
    __syncthreads();
    const int base = s_base;
    for (int i = tid; i < cnt; i += 256)
        if (base + i < PAIR_CAP) pairs[base + i] = s_pairs[i];
}

// ---------------- dot: one 16-lane group per pair, single sweep -----------
// grid = DOT_BLOCKS x 256 threads (16 groups/block)
__global__ __launch_bounds__(256) void dot_kernel(
    const float* __restrict__ train, const float* __restrict__ z_norm,
    const unsigned* __restrict__ pairs, const int* __restrict__ npairs,
    int* __restrict__ counters, float* __restrict__ simbuf)
{
    const int lane = threadIdx.x & 15;                    // lane within group
    const int g0 = blockIdx.x * 16 + (threadIdx.x >> 4);  // group id
    const int ngroups = DOT_BLOCKS * 16;                  // 36864
    const int np = min(*npairs, PAIR_CAP);

    for (int i = g0; i < np; i += ngroups) {
        const unsigned pr = pairs[i];
        const float4* __restrict__ row4 = (const float4*)(train  + (size_t)(pr >> 8)   * D);
        const float4* __restrict__ zr4  = (const float4*)(z_norm + (size_t)(pr & 255u) * D);

        // 16 independent float4 loads per lane; each instruction is a
        // contiguous 256B segment per group (row4[j*16 + lane]).
        float4 r[8], zz[8];
        #pragma unroll
        for (int j = 0; j < 8; j++) r[j]  = row4[j * 16 + lane];
        #pragma unroll
        for (int j = 0; j < 8; j++) zz[j] = zr4[j * 16 + lane];

        float ss = 0.0f, dd = 0.0f;
        #pragma unroll
        for (int j = 0; j < 8; j++) {
            ss += r[j].x*r[j].x  + r[j].y*r[j].y  + r[j].z*r[j].z  + r[j].w*r[j].w;
            dd += r[j].x*zz[j].x + r[j].y*zz[j].y + r[j].z*zz[j].z + r[j].w*zz[j].w;
        }
        #pragma unroll
        for (int m = 1; m < 16; m <<= 1) {
            ss += __shfl_xor(ss, m, 64);
            dd += __shfl_xor(dd, m, 64);
        }
        if (lane == 0) {
            const int b = (int)(pr & 255u);
            const float sim = dd / fmaxf(sqrtf(ss), 1e-12f);
            const int idx = atomicAdd(&counters[b * CSTRIDE], 1);
            if (idx < SLOTS) simbuf[(size_t)b * SLOTS + idx] = sim;
        }
    }
}

// ---------------- topk: one wave per b, 5x wave-max, atomic into out ------
// grid = 256 blocks x 64 threads
__global__ __launch_bounds__(64) void topk_kernel(
    const int* __restrict__ counters, const float* __restrict__ simbuf,
    float* __restrict__ out, int Bt)
{
    const int b = blockIdx.x;
    const int lane = threadIdx.x;
    const int cnt = counters[b * CSTRIDE];
    const int m = min(cnt, SLOTS);
    const float* buf = simbuf + (size_t)b * SLOTS;

    float v[8];
    #pragma unroll
    for (int k = 0; k < 8; k++) {
        const int i = lane + k * 64;
        v[k] = (i < m) ? buf[i] : -1e30f;
    }

    float s = 0.0f;
    #pragma unroll
    for (int r = 0; r < K_NEI; r++) {
        float best = v[0];
        #pragma unroll
        for (int k = 1; k < 8; k++) best = fmaxf(best, v[k]);
        float M = best;
        #pragma unroll
        for (int mm = 1; mm < 64; mm <<= 1) M = fmaxf(M, __shfl_xor(M, mm, 64));
        s += fmaxf(M, 0.0f);   // N-cnt exact zeros from unmatched entries dominate negatives
        const unsigned long long bal = __ballot(best == M);
        const int first = __ffsll(bal) - 1;
        if (lane == first) {
            if      (v[0] == M) v[0] = -1e30f;
            else if (v[1] == M) v[1] = -1e30f;
            else if (v[2] == M) v[2] = -1e30f;
            else if (v[3] == M) v[3] = -1e30f;
            else if (v[4] == M) v[4] = -1e30f;
            else if (v[5] == M) v[5] = -1e30f;
            else if (v[6] == M) v[6] = -1e30f;
            else                v[7] = -1e30f;
        }
    }

    if (lane == 0) {
        const float contrib = (cnt >= K_NEI) ? (1.0f - s * (1.0f / K_NEI)) : 0.0f;
        atomicAdd(out, contrib / (float)Bt);
    }
}

extern "C" void kernel_launch(void* const* d_in, const int* in_sizes, int n_in,
                              void* d_out, int out_size, void* d_ws, size_t ws_size,
                              hipStream_t stream)
{
    const float* z      = (const float*)d_in[0];   // [B, D] f32
    const int*   tattr  = (const int*)d_in[1];     // [B, A] i32
    const float* train  = (const float*)d_in[2];   // [N, D] f32
    const int*   trattr = (const int*)d_in[3];     // [N, A] i32
    float* out = (float*)d_out;

    const int B = in_sizes[0] / D;     // 256
    const int N = in_sizes[2] / D;     // 50000

    // ws layout
    char* ws = (char*)d_ws;
    float*    z_norm   = (float*)ws;    ws += (size_t)B * D * sizeof(float);
    unsigned* tpacked  = (unsigned*)ws; ws += (size_t)B * sizeof(unsigned);
    int*      counters = (int*)ws;      ws += (size_t)B * CSTRIDE * sizeof(int);
    float*    simbuf   = (float*)ws;    ws += (size_t)B * SLOTS * sizeof(float);
    int*      npairs   = (int*)ws;      ws += 64;
    unsigned* pairs    = (unsigned*)ws;

    prep_kernel<<<B, 64, 0, stream>>>(z, tattr, z_norm, tpacked, counters, npairs, out);
    match_kernel<<<(N + 255) / 256, 256, 0, stream>>>(trattr, tpacked, pairs, npairs, N);
    dot_kernel<<<DOT_BLOCKS, 256, 0, stream>>>(train, z_norm, pairs, npairs, counters, simbuf);
    topk_kernel<<<B, 64, 0, stream>>>(counters, simbuf, out, B);
}